// Round 11
// baseline (794.555 us; speedup 1.0000x reference)
//
#include <hip/hip_runtime.h>

#define N_NODES 100000
#define N_EDGES 1200000
#define DIM 64
#define SCAN_BLOCK 256
#define NB ((N_NODES + SCAN_BLOCK - 1) / SCAN_BLOCK)  // 391
#define NSHARD 8
#define NQUAD (N_EDGES / 4)  // 300000

__device__ __forceinline__ float lane_bcast(float v, int k) {
  return __int_as_float(__builtin_amdgcn_readlane(__float_as_int(v), k));
}

__device__ __forceinline__ float lane_pull(float v, int byte_idx) {
  return __int_as_float(__builtin_amdgcn_ds_bpermute(byte_idx, __float_as_int(v)));
}

// butterfly-sum a float4 across the four 16-lane groups (xor 16, then 32)
__device__ __forceinline__ float4 qsum(float4 v) {
  v.x += __shfl_xor(v.x, 16); v.y += __shfl_xor(v.y, 16);
  v.z += __shfl_xor(v.z, 16); v.w += __shfl_xor(v.w, 16);
  v.x += __shfl_xor(v.x, 32); v.y += __shfl_xor(v.y, 32);
  v.z += __shfl_xor(v.z, 32); v.w += __shfl_xor(v.w, 32);
  return v;
}

// ---- CSR build (8-way sharded; int4 = 4 edges/thread) ----------------------

__global__ __launch_bounds__(256) void hist_deg_s(
    const int* __restrict__ dst, int* __restrict__ deg_s, int nQuads) {
  int t = blockIdx.x * 256 + threadIdx.x;
  int shard = blockIdx.x & (NSHARD - 1);
  if (t < nQuads) {
    int4 d = reinterpret_cast<const int4*>(dst)[t];
    int* base = deg_s + (size_t)shard * N_NODES;
    atomicAdd(&base[d.x], 1);
    atomicAdd(&base[d.y], 1);
    atomicAdd(&base[d.z], 1);
    atomicAdd(&base[d.w], 1);
  }
}

__global__ __launch_bounds__(SCAN_BLOCK) void block_sums(
    const int* __restrict__ deg_s, int* __restrict__ bsums, int n) {
  __shared__ int s[SCAN_BLOCK];
  int i = blockIdx.x * SCAN_BLOCK + threadIdx.x;
  int d = 0;
  if (i < n) {
#pragma unroll
    for (int sh = 0; sh < NSHARD; ++sh) d += deg_s[(size_t)sh * N_NODES + i];
  }
  s[threadIdx.x] = d;
  __syncthreads();
  for (int off = SCAN_BLOCK / 2; off > 0; off >>= 1) {
    if (threadIdx.x < off) s[threadIdx.x] += s[threadIdx.x + off];
    __syncthreads();
  }
  if (threadIdx.x == 0) bsums[blockIdx.x] = s[0];
}

__global__ __launch_bounds__(512) void scan_bsums(int* __restrict__ bsums, int nb) {
  __shared__ int s[512];
  int tid = threadIdx.x;
  s[tid] = (tid < nb) ? bsums[tid] : 0;
  __syncthreads();
  for (int off = 1; off < 512; off <<= 1) {
    int v = (tid >= off) ? s[tid - off] : 0;
    __syncthreads();
    s[tid] += v;
    __syncthreads();
  }
  if (tid < nb) bsums[tid] = (tid == 0) ? 0 : s[tid - 1];  // exclusive base
}

// per-block inclusive scan + block base -> offs; also per-shard cursor bases
__global__ __launch_bounds__(SCAN_BLOCK) void scan_final(
    const int* __restrict__ deg_s, const int* __restrict__ bbase,
    int* __restrict__ offs, int* __restrict__ cursor_s, int n) {
  __shared__ int s[SCAN_BLOCK];
  int i = blockIdx.x * SCAN_BLOCK + threadIdx.x;
  int ds0 = 0, ds1 = 0, ds2 = 0, ds3 = 0, ds4 = 0, ds5 = 0, ds6 = 0, ds7 = 0;
  int v = 0;
  if (i < n) {
    ds0 = deg_s[0ul * N_NODES + i]; ds1 = deg_s[1ul * N_NODES + i];
    ds2 = deg_s[2ul * N_NODES + i]; ds3 = deg_s[3ul * N_NODES + i];
    ds4 = deg_s[4ul * N_NODES + i]; ds5 = deg_s[5ul * N_NODES + i];
    ds6 = deg_s[6ul * N_NODES + i]; ds7 = deg_s[7ul * N_NODES + i];
    v = ((ds0 + ds1) + (ds2 + ds3)) + ((ds4 + ds5) + (ds6 + ds7));
  }
  s[threadIdx.x] = v;
  __syncthreads();
  for (int off = 1; off < SCAN_BLOCK; off <<= 1) {
    int t = (threadIdx.x >= off) ? s[threadIdx.x - off] : 0;
    __syncthreads();
    s[threadIdx.x] += t;
    __syncthreads();
  }
  int base = bbase[blockIdx.x];
  if (i < n) {
    int run = base + s[threadIdx.x] - v;  // exclusive
    offs[i] = run;
    cursor_s[0ul * N_NODES + i] = run; run += ds0;
    cursor_s[1ul * N_NODES + i] = run; run += ds1;
    cursor_s[2ul * N_NODES + i] = run; run += ds2;
    cursor_s[3ul * N_NODES + i] = run; run += ds3;
    cursor_s[4ul * N_NODES + i] = run; run += ds4;
    cursor_s[5ul * N_NODES + i] = run; run += ds5;
    cursor_s[6ul * N_NODES + i] = run; run += ds6;
    cursor_s[7ul * N_NODES + i] = run;
  }
  if (i == n - 1) offs[n] = base + s[threadIdx.x];
}

__global__ __launch_bounds__(256) void fill_csr_s(
    const int* __restrict__ src, const int* __restrict__ dst,
    int* __restrict__ cursor_s, int* __restrict__ csr_src, int nQuads) {
  int t = blockIdx.x * 256 + threadIdx.x;
  int shard = blockIdx.x & (NSHARD - 1);
  if (t < nQuads) {
    int4 d = reinterpret_cast<const int4*>(dst)[t];
    int4 sv = reinterpret_cast<const int4*>(src)[t];
    int* cur = cursor_s + (size_t)shard * N_NODES;
    csr_src[atomicAdd(&cur[d.x], 1)] = sv.x;
    csr_src[atomicAdd(&cur[d.y], 1)] = sv.y;
    csr_src[atomicAdd(&cur[d.z], 1)] = sv.z;
    csr_src[atomicAdd(&cur[d.w], 1)] = sv.w;
  }
}

// ---- Fused SAGE layer v7 --------------------------------------------------
// Gather: (q=lane>>4, r=lane&15); one b128 gathers 4 edges x 16 B/lane,
// branch-free, mean scale folded in; cross-q reduce via shfl_xor(16,32);
// r-layout -> j-layout transpose via 4 ds_bpermute + selects (no LDS buffer
// -> LDS exactly 32 KB -> 5 blocks/CU, was 4). launch_bounds(256,5) caps
// VGPR ~102 vs round-9 demand 88. Matvec: proven-clean round-5/9 form (no
// private arrays — rounds 6/7: indexed arrays demote to scratch, ~1 GB/disp).
__global__ __launch_bounds__(256, 5) void sage_fused(
    const float* __restrict__ xin, const int* __restrict__ offs,
    const int* __restrict__ csr_src, const float* __restrict__ Wn,
    const float* __restrict__ Ws, const float* __restrict__ bias,
    float* __restrict__ out, int nNodes) {
  __shared__ float sWn[DIM * DIM];
  __shared__ float sWs[DIM * DIM];
  for (int i = threadIdx.x; i < DIM * DIM / 4; i += 256) {
    reinterpret_cast<float4*>(sWn)[i] = reinterpret_cast<const float4*>(Wn)[i];
    reinterpret_cast<float4*>(sWs)[i] = reinterpret_cast<const float4*>(Ws)[i];
  }
  __syncthreads();

  const float4* xr = reinterpret_cast<const float4*>(xin);
  int lane = threadIdx.x & 63;
  int q = lane >> 4;          // edge subgroup 0..3
  int r = lane & 15;          // float4 column 0..15
  int j = lane;               // output dim
  int w = threadIdx.x >> 6;
  float bj = bias[j];
  int pull = (j >> 2) * 4;    // bpermute byte index: source lane j>>2
  int c = j & 3;              // component of that lane's float4
  int gw = blockIdx.x * 4 + w;
  int nw = gridDim.x * 4;

  for (int p = gw; 2 * p < nNodes; p += nw) {
    int n0 = 2 * p, n1 = 2 * p + 1;
    int e0a = offs[n0], e1a = offs[n0 + 1];
    int e0b = offs[n1], e1b = offs[n1 + 1];
    float inv0 = 1.0f / fmaxf((float)(e1a - e0a), 1.0f);
    float inv1 = 1.0f / fmaxf((float)(e1b - e0b), 1.0f);
    float self0 = xin[(size_t)n0 * DIM + j];
    float self1 = xin[(size_t)n1 * DIM + j];

    // branch-free dual-node float4 gather, mean scale folded in
    float4 A = {0, 0, 0, 0}, B = {0, 0, 0, 0};
    int ea = e0a + q, eb = e0b + q;
    int rem = max(e1a - e0a, e1b - e0b);
    for (; rem > 0; rem -= 4, ea += 4, eb += 4) {
      int ca = max(min(ea, e1a - 1), 0);   // always a valid csr index
      int cb = max(min(eb, e1b - 1), 0);
      int sa = csr_src[ca];
      int sb = csr_src[cb];
      float fa = (ea < e1a) ? inv0 : 0.0f;
      float fb = (eb < e1b) ? inv1 : 0.0f;
      float4 va = xr[(size_t)sa * 16 + r];
      float4 vb = xr[(size_t)sb * 16 + r];
      A.x = fmaf(va.x, fa, A.x); A.y = fmaf(va.y, fa, A.y);
      A.z = fmaf(va.z, fa, A.z); A.w = fmaf(va.w, fa, A.w);
      B.x = fmaf(vb.x, fb, B.x); B.y = fmaf(vb.y, fb, B.y);
      B.z = fmaf(vb.z, fb, B.z); B.w = fmaf(vb.w, fb, B.w);
    }
    A = qsum(A);  // lanes of equal r (all q) hold mean dims [4r,4r+4)
    B = qsum(B);
    // transpose to j-layout: lane j pulls component c of lane (j>>2)'s float4
    float ax = lane_pull(A.x, pull), ay = lane_pull(A.y, pull);
    float az = lane_pull(A.z, pull), aw = lane_pull(A.w, pull);
    float mean0 = (c == 0) ? ax : (c == 1) ? ay : (c == 2) ? az : aw;
    float bx = lane_pull(B.x, pull), by = lane_pull(B.y, pull);
    float bz = lane_pull(B.z, pull), bw = lane_pull(B.w, pull);
    float mean1 = (c == 0) ? bx : (c == 1) ? by : (c == 2) ? bz : bw;

    // matvec: 4 independent chains, readlane with wave-uniform k
    float a0n = bj, a0s = 0.f, a1n = bj, a1s = 0.f;
#pragma unroll
    for (int k = 0; k < DIM; ++k) {
      float wnk = sWn[k * DIM + j];
      float wsk = sWs[k * DIM + j];
      a0n = fmaf(lane_bcast(mean0, k), wnk, a0n);
      a0s = fmaf(lane_bcast(self0, k), wsk, a0s);
      a1n = fmaf(lane_bcast(mean1, k), wnk, a1n);
      a1s = fmaf(lane_bcast(self1, k), wsk, a1s);
    }
    out[(size_t)n0 * DIM + j] = fmaxf(a0n + a0s, 0.0f);
    out[(size_t)n1 * DIM + j] = fmaxf(a1n + a1s, 0.0f);
  }
}

extern "C" void kernel_launch(void* const* d_in, const int* in_sizes, int n_in,
                              void* d_out, int out_size, void* d_ws, size_t ws_size,
                              hipStream_t stream) {
  const float* x   = (const float*)d_in[0];
  const int*   ei  = (const int*)d_in[1];
  const float* Wn1 = (const float*)d_in[2];
  const float* Ws1 = (const float*)d_in[3];
  const float* b1  = (const float*)d_in[4];
  const float* Wn2 = (const float*)d_in[5];
  const float* Ws2 = (const float*)d_in[6];
  const float* b2  = (const float*)d_in[7];
  const int* src = ei;
  const int* dst = ei + N_EDGES;

  // ws (ints): deg_s[8N] | offs[N+1] | cursor_s[8N] | bsums[512] | csr[E] | h1[N*64]f
  int* deg_s    = (int*)d_ws;
  int* offs     = deg_s + (size_t)NSHARD * N_NODES;
  int* cursor_s = offs + N_NODES + 1;
  int* bsums    = cursor_s + (size_t)NSHARD * N_NODES;
  int* csr      = bsums + 512;
  float* h1     = (float*)(csr + N_EDGES);
  float* outp   = (float*)d_out;

  const int quadBlocks = (NQUAD + 255) / 256;  // 1172
  const int fusedBlocks = 1280;                // 5 blocks/CU, 20 waves/CU

  hipMemsetAsync(deg_s, 0, (size_t)NSHARD * N_NODES * sizeof(int), stream);
  hist_deg_s<<<quadBlocks, 256, 0, stream>>>(dst, deg_s, NQUAD);
  block_sums<<<NB, SCAN_BLOCK, 0, stream>>>(deg_s, bsums, N_NODES);
  scan_bsums<<<1, 512, 0, stream>>>(bsums, NB);
  scan_final<<<NB, SCAN_BLOCK, 0, stream>>>(deg_s, bsums, offs, cursor_s, N_NODES);
  fill_csr_s<<<quadBlocks, 256, 0, stream>>>(src, dst, cursor_s, csr, NQUAD);

  sage_fused<<<fusedBlocks, 256, 0, stream>>>(x, offs, csr, Wn1, Ws1, b1, h1, N_NODES);
  sage_fused<<<fusedBlocks, 256, 0, stream>>>(h1, offs, csr, Wn2, Ws2, b2, outp, N_NODES);
}

// Round 13
// 524.311 us; speedup vs baseline: 1.5154x; 1.5154x over previous
//
#include <hip/hip_runtime.h>

#define N_NODES 100000
#define N_EDGES 1200000
#define DIM 64
#define SCAN_BLOCK 256
#define NB ((N_NODES + SCAN_BLOCK - 1) / SCAN_BLOCK)  // 391
#define NSHARD 8
#define NQUAD (N_EDGES / 4)  // 300000

__device__ __forceinline__ float lane_bcast(float v, int k) {
  return __int_as_float(__builtin_amdgcn_readlane(__float_as_int(v), k));
}

__device__ __forceinline__ float lane_pull(float v, int byte_idx) {
  return __int_as_float(__builtin_amdgcn_ds_bpermute(byte_idx, __float_as_int(v)));
}

// butterfly-sum a float4 across the four 16-lane groups (xor 16, then 32)
__device__ __forceinline__ float4 qsum(float4 v) {
  v.x += __shfl_xor(v.x, 16); v.y += __shfl_xor(v.y, 16);
  v.z += __shfl_xor(v.z, 16); v.w += __shfl_xor(v.w, 16);
  v.x += __shfl_xor(v.x, 32); v.y += __shfl_xor(v.y, 32);
  v.z += __shfl_xor(v.z, 32); v.w += __shfl_xor(v.w, 32);
  return v;
}

// ---- CSR build (8-way sharded; int4 = 4 edges/thread) ----------------------

__global__ __launch_bounds__(256) void hist_deg_s(
    const int* __restrict__ dst, int* __restrict__ deg_s, int nQuads) {
  int t = blockIdx.x * 256 + threadIdx.x;
  int shard = blockIdx.x & (NSHARD - 1);
  if (t < nQuads) {
    int4 d = reinterpret_cast<const int4*>(dst)[t];
    int* base = deg_s + (size_t)shard * N_NODES;
    atomicAdd(&base[d.x], 1);
    atomicAdd(&base[d.y], 1);
    atomicAdd(&base[d.z], 1);
    atomicAdd(&base[d.w], 1);
  }
}

__global__ __launch_bounds__(SCAN_BLOCK) void block_sums(
    const int* __restrict__ deg_s, int* __restrict__ bsums, int n) {
  __shared__ int s[SCAN_BLOCK];
  int i = blockIdx.x * SCAN_BLOCK + threadIdx.x;
  int d = 0;
  if (i < n) {
#pragma unroll
    for (int sh = 0; sh < NSHARD; ++sh) d += deg_s[(size_t)sh * N_NODES + i];
  }
  s[threadIdx.x] = d;
  __syncthreads();
  for (int off = SCAN_BLOCK / 2; off > 0; off >>= 1) {
    if (threadIdx.x < off) s[threadIdx.x] += s[threadIdx.x + off];
    __syncthreads();
  }
  if (threadIdx.x == 0) bsums[blockIdx.x] = s[0];
}

__global__ __launch_bounds__(512) void scan_bsums(int* __restrict__ bsums, int nb) {
  __shared__ int s[512];
  int tid = threadIdx.x;
  s[tid] = (tid < nb) ? bsums[tid] : 0;
  __syncthreads();
  for (int off = 1; off < 512; off <<= 1) {
    int v = (tid >= off) ? s[tid - off] : 0;
    __syncthreads();
    s[tid] += v;
    __syncthreads();
  }
  if (tid < nb) bsums[tid] = (tid == 0) ? 0 : s[tid - 1];  // exclusive base
}

// per-block inclusive scan + block base -> offs; also per-shard cursor bases
__global__ __launch_bounds__(SCAN_BLOCK) void scan_final(
    const int* __restrict__ deg_s, const int* __restrict__ bbase,
    int* __restrict__ offs, int* __restrict__ cursor_s, int n) {
  __shared__ int s[SCAN_BLOCK];
  int i = blockIdx.x * SCAN_BLOCK + threadIdx.x;
  int ds0 = 0, ds1 = 0, ds2 = 0, ds3 = 0, ds4 = 0, ds5 = 0, ds6 = 0, ds7 = 0;
  int v = 0;
  if (i < n) {
    ds0 = deg_s[0ul * N_NODES + i]; ds1 = deg_s[1ul * N_NODES + i];
    ds2 = deg_s[2ul * N_NODES + i]; ds3 = deg_s[3ul * N_NODES + i];
    ds4 = deg_s[4ul * N_NODES + i]; ds5 = deg_s[5ul * N_NODES + i];
    ds6 = deg_s[6ul * N_NODES + i]; ds7 = deg_s[7ul * N_NODES + i];
    v = ((ds0 + ds1) + (ds2 + ds3)) + ((ds4 + ds5) + (ds6 + ds7));
  }
  s[threadIdx.x] = v;
  __syncthreads();
  for (int off = 1; off < SCAN_BLOCK; off <<= 1) {
    int t = (threadIdx.x >= off) ? s[threadIdx.x - off] : 0;
    __syncthreads();
    s[threadIdx.x] += t;
    __syncthreads();
  }
  int base = bbase[blockIdx.x];
  if (i < n) {
    int run = base + s[threadIdx.x] - v;  // exclusive
    offs[i] = run;
    cursor_s[0ul * N_NODES + i] = run; run += ds0;
    cursor_s[1ul * N_NODES + i] = run; run += ds1;
    cursor_s[2ul * N_NODES + i] = run; run += ds2;
    cursor_s[3ul * N_NODES + i] = run; run += ds3;
    cursor_s[4ul * N_NODES + i] = run; run += ds4;
    cursor_s[5ul * N_NODES + i] = run; run += ds5;
    cursor_s[6ul * N_NODES + i] = run; run += ds6;
    cursor_s[7ul * N_NODES + i] = run;
  }
  if (i == n - 1) offs[n] = base + s[threadIdx.x];
}

__global__ __launch_bounds__(256) void fill_csr_s(
    const int* __restrict__ src, const int* __restrict__ dst,
    int* __restrict__ cursor_s, int* __restrict__ csr_src, int nQuads) {
  int t = blockIdx.x * 256 + threadIdx.x;
  int shard = blockIdx.x & (NSHARD - 1);
  if (t < nQuads) {
    int4 d = reinterpret_cast<const int4*>(dst)[t];
    int4 sv = reinterpret_cast<const int4*>(src)[t];
    int* cur = cursor_s + (size_t)shard * N_NODES;
    csr_src[atomicAdd(&cur[d.x], 1)] = sv.x;
    csr_src[atomicAdd(&cur[d.y], 1)] = sv.y;
    csr_src[atomicAdd(&cur[d.z], 1)] = sv.z;
    csr_src[atomicAdd(&cur[d.w], 1)] = sv.w;
  }
}

// ---- Fused SAGE layer v8 --------------------------------------------------
// = round-9's proven-clean kernel (VGPR 88, zero scratch, 136 us) with the sT
// LDS buffer replaced by a ds_bpermute transpose -> LDS exactly 32 KB.
// PLAIN __launch_bounds__(256): rounds 6 and 11 both proved that a min-waves
// hint makes the allocator cap VGPRs below demand -> scratch spill in the
// gather loop (r11: VGPR 48, FETCH 569 MB, 2.2x slower). Never again.
// If VGPR stays <= 102, HW gives 5 waves/SIMD + 5 blocks/CU (LDS fits);
// worst case it lands back at round-9 occupancy. No private indexed arrays
// anywhere (r6/r7 lesson: they demote to scratch).
__global__ __launch_bounds__(256) void sage_fused(
    const float* __restrict__ xin, const int* __restrict__ offs,
    const int* __restrict__ csr_src, const float* __restrict__ Wn,
    const float* __restrict__ Ws, const float* __restrict__ bias,
    float* __restrict__ out, int nNodes) {
  __shared__ float sWn[DIM * DIM];
  __shared__ float sWs[DIM * DIM];
  for (int i = threadIdx.x; i < DIM * DIM / 4; i += 256) {
    reinterpret_cast<float4*>(sWn)[i] = reinterpret_cast<const float4*>(Wn)[i];
    reinterpret_cast<float4*>(sWs)[i] = reinterpret_cast<const float4*>(Ws)[i];
  }
  __syncthreads();

  const float4* xr = reinterpret_cast<const float4*>(xin);
  int lane = threadIdx.x & 63;
  int q = lane >> 4;          // edge subgroup 0..3
  int r = lane & 15;          // float4 column 0..15
  int j = lane;               // output dim
  int w = threadIdx.x >> 6;
  float bj = bias[j];
  int pull = (j >> 2) * 4;    // bpermute byte index: source lane j>>2
  int c = j & 3;              // component of that lane's float4
  int gw = blockIdx.x * 4 + w;
  int nw = gridDim.x * 4;

  for (int p = gw; 2 * p < nNodes; p += nw) {
    int n0 = 2 * p, n1 = 2 * p + 1;
    int e0a = offs[n0], e1a = offs[n0 + 1];
    int e0b = offs[n1], e1b = offs[n1 + 1];
    float inv0 = 1.0f / fmaxf((float)(e1a - e0a), 1.0f);
    float inv1 = 1.0f / fmaxf((float)(e1b - e0b), 1.0f);
    float self0 = xin[(size_t)n0 * DIM + j];
    float self1 = xin[(size_t)n1 * DIM + j];

    // branch-free dual-node float4 gather, mean scale folded in
    float4 A = {0, 0, 0, 0}, B = {0, 0, 0, 0};
    int ea = e0a + q, eb = e0b + q;
    int rem = max(e1a - e0a, e1b - e0b);
    for (; rem > 0; rem -= 4, ea += 4, eb += 4) {
      int ca = max(min(ea, e1a - 1), 0);   // always a valid csr index
      int cb = max(min(eb, e1b - 1), 0);
      int sa = csr_src[ca];
      int sb = csr_src[cb];
      float fa = (ea < e1a) ? inv0 : 0.0f;
      float fb = (eb < e1b) ? inv1 : 0.0f;
      float4 va = xr[(size_t)sa * 16 + r];
      float4 vb = xr[(size_t)sb * 16 + r];
      A.x = fmaf(va.x, fa, A.x); A.y = fmaf(va.y, fa, A.y);
      A.z = fmaf(va.z, fa, A.z); A.w = fmaf(va.w, fa, A.w);
      B.x = fmaf(vb.x, fb, B.x); B.y = fmaf(vb.y, fb, B.y);
      B.z = fmaf(vb.z, fb, B.z); B.w = fmaf(vb.w, fb, B.w);
    }
    A = qsum(A);  // lanes of equal r (all q) hold mean dims [4r,4r+4)
    B = qsum(B);
    // transpose to j-layout: lane j pulls component c of lane (j>>2)'s float4
    float ax = lane_pull(A.x, pull), ay = lane_pull(A.y, pull);
    float az = lane_pull(A.z, pull), aw = lane_pull(A.w, pull);
    float mean0 = (c == 0) ? ax : (c == 1) ? ay : (c == 2) ? az : aw;
    float bx = lane_pull(B.x, pull), by = lane_pull(B.y, pull);
    float bz = lane_pull(B.z, pull), bw = lane_pull(B.w, pull);
    float mean1 = (c == 0) ? bx : (c == 1) ? by : (c == 2) ? bz : bw;

    // matvec: 4 independent chains, readlane with wave-uniform k
    float a0n = bj, a0s = 0.f, a1n = bj, a1s = 0.f;
#pragma unroll
    for (int k = 0; k < DIM; ++k) {
      float wnk = sWn[k * DIM + j];
      float wsk = sWs[k * DIM + j];
      a0n = fmaf(lane_bcast(mean0, k), wnk, a0n);
      a0s = fmaf(lane_bcast(self0, k), wsk, a0s);
      a1n = fmaf(lane_bcast(mean1, k), wnk, a1n);
      a1s = fmaf(lane_bcast(self1, k), wsk, a1s);
    }
    out[(size_t)n0 * DIM + j] = fmaxf(a0n + a0s, 0.0f);
    out[(size_t)n1 * DIM + j] = fmaxf(a1n + a1s, 0.0f);
  }
}

extern "C" void kernel_launch(void* const* d_in, const int* in_sizes, int n_in,
                              void* d_out, int out_size, void* d_ws, size_t ws_size,
                              hipStream_t stream) {
  const float* x   = (const float*)d_in[0];
  const int*   ei  = (const int*)d_in[1];
  const float* Wn1 = (const float*)d_in[2];
  const float* Ws1 = (const float*)d_in[3];
  const float* b1  = (const float*)d_in[4];
  const float* Wn2 = (const float*)d_in[5];
  const float* Ws2 = (const float*)d_in[6];
  const float* b2  = (const float*)d_in[7];
  const int* src = ei;
  const int* dst = ei + N_EDGES;

  // ws (ints): deg_s[8N] | offs[N+1] | cursor_s[8N] | bsums[512] | csr[E] | h1[N*64]f
  int* deg_s    = (int*)d_ws;
  int* offs     = deg_s + (size_t)NSHARD * N_NODES;
  int* cursor_s = offs + N_NODES + 1;
  int* bsums    = cursor_s + (size_t)NSHARD * N_NODES;
  int* csr      = bsums + 512;
  float* h1     = (float*)(csr + N_EDGES);
  float* outp   = (float*)d_out;

  const int quadBlocks = (NQUAD + 255) / 256;  // 1172
  const int fusedBlocks = 1280;                // 5 blocks/CU if VGPR<=102

  hipMemsetAsync(deg_s, 0, (size_t)NSHARD * N_NODES * sizeof(int), stream);
  hist_deg_s<<<quadBlocks, 256, 0, stream>>>(dst, deg_s, NQUAD);
  block_sums<<<NB, SCAN_BLOCK, 0, stream>>>(deg_s, bsums, N_NODES);
  scan_bsums<<<1, 512, 0, stream>>>(bsums, NB);
  scan_final<<<NB, SCAN_BLOCK, 0, stream>>>(deg_s, bsums, offs, cursor_s, N_NODES);
  fill_csr_s<<<quadBlocks, 256, 0, stream>>>(src, dst, cursor_s, csr, NQUAD);

  sage_fused<<<fusedBlocks, 256, 0, stream>>>(x, offs, csr, Wn1, Ws1, b1, h1, N_NODES);
  sage_fused<<<fusedBlocks, 256, 0, stream>>>(h1, offs, csr, Wn2, Ws2, b2, outp, N_NODES);
}

// Round 14
// 518.622 us; speedup vs baseline: 1.5320x; 1.0110x over previous
//
#include <hip/hip_runtime.h>

#define N_NODES 100000
#define N_EDGES 1200000
#define DIM 64
#define SCAN_BLOCK 256
#define NB ((N_NODES + SCAN_BLOCK - 1) / SCAN_BLOCK)  // 391
#define NSHARD 8
#define NQUAD (N_EDGES / 4)  // 300000

__device__ __forceinline__ float lane_bcast(float v, int k) {
  return __int_as_float(__builtin_amdgcn_readlane(__float_as_int(v), k));
}

// butterfly-sum a float4 across the four 16-lane groups (xor 16, then 32);
// afterwards EVERY lane holds the full sum for its r = lane&15
__device__ __forceinline__ float4 qsum(float4 v) {
  v.x += __shfl_xor(v.x, 16); v.y += __shfl_xor(v.y, 16);
  v.z += __shfl_xor(v.z, 16); v.w += __shfl_xor(v.w, 16);
  v.x += __shfl_xor(v.x, 32); v.y += __shfl_xor(v.y, 32);
  v.z += __shfl_xor(v.z, 32); v.w += __shfl_xor(v.w, 32);
  return v;
}

// ---- CSR build (8-way sharded; int4 = 4 edges/thread) ----------------------

__global__ __launch_bounds__(256) void hist_deg_s(
    const int* __restrict__ dst, int* __restrict__ deg_s, int nQuads) {
  int t = blockIdx.x * 256 + threadIdx.x;
  int shard = blockIdx.x & (NSHARD - 1);
  if (t < nQuads) {
    int4 d = reinterpret_cast<const int4*>(dst)[t];
    int* base = deg_s + (size_t)shard * N_NODES;
    atomicAdd(&base[d.x], 1);
    atomicAdd(&base[d.y], 1);
    atomicAdd(&base[d.z], 1);
    atomicAdd(&base[d.w], 1);
  }
}

__global__ __launch_bounds__(SCAN_BLOCK) void block_sums(
    const int* __restrict__ deg_s, int* __restrict__ bsums, int n) {
  __shared__ int s[SCAN_BLOCK];
  int i = blockIdx.x * SCAN_BLOCK + threadIdx.x;
  int d = 0;
  if (i < n) {
#pragma unroll
    for (int sh = 0; sh < NSHARD; ++sh) d += deg_s[(size_t)sh * N_NODES + i];
  }
  s[threadIdx.x] = d;
  __syncthreads();
  for (int off = SCAN_BLOCK / 2; off > 0; off >>= 1) {
    if (threadIdx.x < off) s[threadIdx.x] += s[threadIdx.x + off];
    __syncthreads();
  }
  if (threadIdx.x == 0) bsums[blockIdx.x] = s[0];
}

__global__ __launch_bounds__(512) void scan_bsums(int* __restrict__ bsums, int nb) {
  __shared__ int s[512];
  int tid = threadIdx.x;
  s[tid] = (tid < nb) ? bsums[tid] : 0;
  __syncthreads();
  for (int off = 1; off < 512; off <<= 1) {
    int v = (tid >= off) ? s[tid - off] : 0;
    __syncthreads();
    s[tid] += v;
    __syncthreads();
  }
  if (tid < nb) bsums[tid] = (tid == 0) ? 0 : s[tid - 1];  // exclusive base
}

// per-block inclusive scan + block base -> offs; also per-shard cursor bases
__global__ __launch_bounds__(SCAN_BLOCK) void scan_final(
    const int* __restrict__ deg_s, const int* __restrict__ bbase,
    int* __restrict__ offs, int* __restrict__ cursor_s, int n) {
  __shared__ int s[SCAN_BLOCK];
  int i = blockIdx.x * SCAN_BLOCK + threadIdx.x;
  int ds0 = 0, ds1 = 0, ds2 = 0, ds3 = 0, ds4 = 0, ds5 = 0, ds6 = 0, ds7 = 0;
  int v = 0;
  if (i < n) {
    ds0 = deg_s[0ul * N_NODES + i]; ds1 = deg_s[1ul * N_NODES + i];
    ds2 = deg_s[2ul * N_NODES + i]; ds3 = deg_s[3ul * N_NODES + i];
    ds4 = deg_s[4ul * N_NODES + i]; ds5 = deg_s[5ul * N_NODES + i];
    ds6 = deg_s[6ul * N_NODES + i]; ds7 = deg_s[7ul * N_NODES + i];
    v = ((ds0 + ds1) + (ds2 + ds3)) + ((ds4 + ds5) + (ds6 + ds7));
  }
  s[threadIdx.x] = v;
  __syncthreads();
  for (int off = 1; off < SCAN_BLOCK; off <<= 1) {
    int t = (threadIdx.x >= off) ? s[threadIdx.x - off] : 0;
    __syncthreads();
    s[threadIdx.x] += t;
    __syncthreads();
  }
  int base = bbase[blockIdx.x];
  if (i < n) {
    int run = base + s[threadIdx.x] - v;  // exclusive
    offs[i] = run;
    cursor_s[0ul * N_NODES + i] = run; run += ds0;
    cursor_s[1ul * N_NODES + i] = run; run += ds1;
    cursor_s[2ul * N_NODES + i] = run; run += ds2;
    cursor_s[3ul * N_NODES + i] = run; run += ds3;
    cursor_s[4ul * N_NODES + i] = run; run += ds4;
    cursor_s[5ul * N_NODES + i] = run; run += ds5;
    cursor_s[6ul * N_NODES + i] = run; run += ds6;
    cursor_s[7ul * N_NODES + i] = run;
  }
  if (i == n - 1) offs[n] = base + s[threadIdx.x];
}

__global__ __launch_bounds__(256) void fill_csr_s(
    const int* __restrict__ src, const int* __restrict__ dst,
    int* __restrict__ cursor_s, int* __restrict__ csr_src, int nQuads) {
  int t = blockIdx.x * 256 + threadIdx.x;
  int shard = blockIdx.x & (NSHARD - 1);
  if (t < nQuads) {
    int4 d = reinterpret_cast<const int4*>(dst)[t];
    int4 sv = reinterpret_cast<const int4*>(src)[t];
    int* cur = cursor_s + (size_t)shard * N_NODES;
    csr_src[atomicAdd(&cur[d.x], 1)] = sv.x;
    csr_src[atomicAdd(&cur[d.y], 1)] = sv.y;
    csr_src[atomicAdd(&cur[d.z], 1)] = sv.z;
    csr_src[atomicAdd(&cur[d.w], 1)] = sv.w;
  }
}

// ---- Fused SAGE layer v9 --------------------------------------------------
// Gather identical to r13 (branch-free float4, mean scale folded, qsum).
// TRANSPOSE ELIMINATED: after qsum every lane holds the full A/B float4
// (lane kr's float4 = mean dims [4kr,4kr+4)), so the matvec reads
// lane_bcast(A.{x|y|z|w}, kr) with the component chosen SYNTACTICALLY in an
// explicit 4-step body — no sT LDS buffer (r9: +2KB, lgkm round-trip), no
// bpermute chain (r13: +20us), and no dynamic component indexing (r6/r7
// scratch trap). LDS exactly 32 KB. PLAIN __launch_bounds__(256) — r6/r11:
// min-waves hints starve VGPRs -> gather-loop spill; never again.
__global__ __launch_bounds__(256) void sage_fused(
    const float* __restrict__ xin, const int* __restrict__ offs,
    const int* __restrict__ csr_src, const float* __restrict__ Wn,
    const float* __restrict__ Ws, const float* __restrict__ bias,
    float* __restrict__ out, int nNodes) {
  __shared__ float sWn[DIM * DIM];
  __shared__ float sWs[DIM * DIM];
  for (int i = threadIdx.x; i < DIM * DIM / 4; i += 256) {
    reinterpret_cast<float4*>(sWn)[i] = reinterpret_cast<const float4*>(Wn)[i];
    reinterpret_cast<float4*>(sWs)[i] = reinterpret_cast<const float4*>(Ws)[i];
  }
  __syncthreads();

  const float4* xr = reinterpret_cast<const float4*>(xin);
  int lane = threadIdx.x & 63;
  int q = lane >> 4;          // edge subgroup 0..3
  int r = lane & 15;          // float4 column 0..15
  int j = lane;               // output dim
  int w = threadIdx.x >> 6;
  float bj = bias[j];
  int gw = blockIdx.x * 4 + w;
  int nw = gridDim.x * 4;

  for (int p = gw; 2 * p < nNodes; p += nw) {
    int n0 = 2 * p, n1 = 2 * p + 1;
    int e0a = offs[n0], e1a = offs[n0 + 1];
    int e0b = offs[n1], e1b = offs[n1 + 1];
    float inv0 = 1.0f / fmaxf((float)(e1a - e0a), 1.0f);
    float inv1 = 1.0f / fmaxf((float)(e1b - e0b), 1.0f);
    float self0 = xin[(size_t)n0 * DIM + j];
    float self1 = xin[(size_t)n1 * DIM + j];

    // branch-free dual-node float4 gather, mean scale folded in
    float4 A = {0, 0, 0, 0}, B = {0, 0, 0, 0};
    int ea = e0a + q, eb = e0b + q;
    int rem = max(e1a - e0a, e1b - e0b);
    for (; rem > 0; rem -= 4, ea += 4, eb += 4) {
      int ca = max(min(ea, e1a - 1), 0);   // always a valid csr index
      int cb = max(min(eb, e1b - 1), 0);
      int sa = csr_src[ca];
      int sb = csr_src[cb];
      float fa = (ea < e1a) ? inv0 : 0.0f;
      float fb = (eb < e1b) ? inv1 : 0.0f;
      float4 va = xr[(size_t)sa * 16 + r];
      float4 vb = xr[(size_t)sb * 16 + r];
      A.x = fmaf(va.x, fa, A.x); A.y = fmaf(va.y, fa, A.y);
      A.z = fmaf(va.z, fa, A.z); A.w = fmaf(va.w, fa, A.w);
      B.x = fmaf(vb.x, fb, B.x); B.y = fmaf(vb.y, fb, B.y);
      B.z = fmaf(vb.z, fb, B.z); B.w = fmaf(vb.w, fb, B.w);
    }
    A = qsum(A);  // every lane now holds full reduced float4 (per its r)
    B = qsum(B);

    // matvec: k = 4*kr + c; mean dim k = component c of lane kr's A/B.
    // Components written out explicitly -> no dynamic indexing possible.
    float a0n = bj, a0s = 0.f, a1n = bj, a1s = 0.f;
#pragma unroll
    for (int kr = 0; kr < 16; ++kr) {
      int k0 = 4 * kr;
      float wn0 = sWn[(k0 + 0) * DIM + j], ws0 = sWs[(k0 + 0) * DIM + j];
      float wn1 = sWn[(k0 + 1) * DIM + j], ws1 = sWs[(k0 + 1) * DIM + j];
      float wn2 = sWn[(k0 + 2) * DIM + j], ws2 = sWs[(k0 + 2) * DIM + j];
      float wn3 = sWn[(k0 + 3) * DIM + j], ws3 = sWs[(k0 + 3) * DIM + j];
      a0n = fmaf(lane_bcast(A.x, kr), wn0, a0n);
      a0n = fmaf(lane_bcast(A.y, kr), wn1, a0n);
      a0n = fmaf(lane_bcast(A.z, kr), wn2, a0n);
      a0n = fmaf(lane_bcast(A.w, kr), wn3, a0n);
      a1n = fmaf(lane_bcast(B.x, kr), wn0, a1n);
      a1n = fmaf(lane_bcast(B.y, kr), wn1, a1n);
      a1n = fmaf(lane_bcast(B.z, kr), wn2, a1n);
      a1n = fmaf(lane_bcast(B.w, kr), wn3, a1n);
      a0s = fmaf(lane_bcast(self0, k0 + 0), ws0, a0s);
      a0s = fmaf(lane_bcast(self0, k0 + 1), ws1, a0s);
      a0s = fmaf(lane_bcast(self0, k0 + 2), ws2, a0s);
      a0s = fmaf(lane_bcast(self0, k0 + 3), ws3, a0s);
      a1s = fmaf(lane_bcast(self1, k0 + 0), ws0, a1s);
      a1s = fmaf(lane_bcast(self1, k0 + 1), ws1, a1s);
      a1s = fmaf(lane_bcast(self1, k0 + 2), ws2, a1s);
      a1s = fmaf(lane_bcast(self1, k0 + 3), ws3, a1s);
    }
    out[(size_t)n0 * DIM + j] = fmaxf(a0n + a0s, 0.0f);
    out[(size_t)n1 * DIM + j] = fmaxf(a1n + a1s, 0.0f);
  }
}

extern "C" void kernel_launch(void* const* d_in, const int* in_sizes, int n_in,
                              void* d_out, int out_size, void* d_ws, size_t ws_size,
                              hipStream_t stream) {
  const float* x   = (const float*)d_in[0];
  const int*   ei  = (const int*)d_in[1];
  const float* Wn1 = (const float*)d_in[2];
  const float* Ws1 = (const float*)d_in[3];
  const float* b1  = (const float*)d_in[4];
  const float* Wn2 = (const float*)d_in[5];
  const float* Ws2 = (const float*)d_in[6];
  const float* b2  = (const float*)d_in[7];
  const int* src = ei;
  const int* dst = ei + N_EDGES;

  // ws (ints): deg_s[8N] | offs[N+1] | cursor_s[8N] | bsums[512] | csr[E] | h1[N*64]f
  int* deg_s    = (int*)d_ws;
  int* offs     = deg_s + (size_t)NSHARD * N_NODES;
  int* cursor_s = offs + N_NODES + 1;
  int* bsums    = cursor_s + (size_t)NSHARD * N_NODES;
  int* csr      = bsums + 512;
  float* h1     = (float*)(csr + N_EDGES);
  float* outp   = (float*)d_out;

  const int quadBlocks = (NQUAD + 255) / 256;  // 1172
  const int fusedBlocks = 1280;                // 5 blocks/CU if VGPR<=102

  hipMemsetAsync(deg_s, 0, (size_t)NSHARD * N_NODES * sizeof(int), stream);
  hist_deg_s<<<quadBlocks, 256, 0, stream>>>(dst, deg_s, NQUAD);
  block_sums<<<NB, SCAN_BLOCK, 0, stream>>>(deg_s, bsums, N_NODES);
  scan_bsums<<<1, 512, 0, stream>>>(bsums, NB);
  scan_final<<<NB, SCAN_BLOCK, 0, stream>>>(deg_s, bsums, offs, cursor_s, N_NODES);
  fill_csr_s<<<quadBlocks, 256, 0, stream>>>(src, dst, cursor_s, csr, NQUAD);

  sage_fused<<<fusedBlocks, 256, 0, stream>>>(x, offs, csr, Wn1, Ws1, b1, h1, N_NODES);
  sage_fused<<<fusedBlocks, 256, 0, stream>>>(h1, offs, csr, Wn2, Ws2, b2, outp, N_NODES);
}